// Round 3
// baseline (1147.959 us; speedup 1.0000x reference)
//
#include <hip/hip_runtime.h>

// PrototypeBank steady-state update, MI355X/gfx950.  Round 3.
//   emb:    [131072, 512] fp32   protos: [1024, 512] fp32
//   out[k]: count>0 ? normalize(0.9*p + 0.1*mean(norm_emb assigned to k)) : p
//
// Round-3 changes vs round 2:
//   - assign: argmax over <e, p_k> with RAW (unnormalized) bf16 e — same argmax,
//     since ||e|| is row-constant.  invnorm still computed (for update).
//   - assign: no persistent argmax registers; per-ng fold -> 8 KB LDS merge
//     buffer.  Peak regs ~112 <= 128 -> 16 waves/CU with ZERO scratch spills
//     (round 2 spilled ~500 MB of HBM traffic under the 128-reg cap).
//   - update: float4 gather, 2 rows in flight (thread-parity split) + unroll.

#define D 512
#define NPROTO 1024
#define ROWS 64          // embedding rows per workgroup in k1

typedef __attribute__((ext_vector_type(8))) unsigned short ushort8;
typedef __attribute__((ext_vector_type(8))) __bf16 bfrag8;
typedef __attribute__((ext_vector_type(4))) float f32x4;

static __device__ inline unsigned short f2bf(float f) {
    unsigned int u = __float_as_uint(f);
    u = u + 0x7FFFu + ((u >> 16) & 1u);   // round-to-nearest-even
    return (unsigned short)(u >> 16);
}

// ---------------- k0: normalize prototypes -> packed bf16 fragments ----------------
// Packed layout: proto-group g (16 protos) x k-step ks (32 cols) -> 1KB chunk at
// pbf + (g*16+ks)*512; consumer lane l reads chunk + l*8 shorts (16B, coalesced).
__global__ __launch_bounds__(256) void norm_protos_kernel(
    const float* __restrict__ protos, unsigned short* __restrict__ pbf,
    int* __restrict__ counts)
{
    const int wave = threadIdx.x >> 6, lane = threadIdx.x & 63;
    const int row = blockIdx.x * 4 + wave;            // grid 256 -> 1024 rows
    const float* src = protos + (size_t)row * D + lane * 8;
    float4 v0 = *(const float4*)src;
    float4 v1 = *(const float4*)(src + 4);
    float ss = v0.x*v0.x + v0.y*v0.y + v0.z*v0.z + v0.w*v0.w
             + v1.x*v1.x + v1.y*v1.y + v1.z*v1.z + v1.w*v1.w;
    #pragma unroll
    for (int off = 32; off > 0; off >>= 1) ss += __shfl_xor(ss, off, 64);
    const float inv = 1.0f / fmaxf(sqrtf(ss), 1e-6f);
    ushort8 w;
    w[0] = f2bf(v0.x*inv); w[1] = f2bf(v0.y*inv); w[2] = f2bf(v0.z*inv); w[3] = f2bf(v0.w*inv);
    w[4] = f2bf(v1.x*inv); w[5] = f2bf(v1.y*inv); w[6] = f2bf(v1.z*inv); w[7] = f2bf(v1.w*inv);
    const int g = row >> 4, cl = row & 15;
    const int ks = lane >> 2, q = lane & 3;           // lane holds cols [lane*8, +8)
    *(ushort8*)(pbf + (size_t)(g * 16 + ks) * 512 + (q * 16 + cl) * 8) = w;
    if (blockIdx.x == 0) ((int4*)counts)[threadIdx.x] = (int4){0, 0, 0, 0};
}

// ---------------- k1: argmax over 1024 protos (bf16 MFMA, raw e) ----------------
// LDS A-tile: 64 rows x 512 bf16, 16B-chunk XOR swizzle (slot = chunk ^ (row&7)).
// 8 waves; wave owns 128 protos as 2 groups of 64 (4x4 MFMA subtiles).
// Per-group argmax folded straight to LDS -> no persistent argmax registers.
__global__ __launch_bounds__(512, 4) void assign_kernel(
    const float* __restrict__ emb, const unsigned short* __restrict__ pbf,
    int* __restrict__ assign, float* __restrict__ invnorm, int* __restrict__ counts)
{
    __shared__ __align__(16) unsigned short eT[ROWS * D];   // 64 KB
    __shared__ float swmax[16][64];                          // 4 KB
    __shared__ int   swidx[16][64];                          // 4 KB
    const int tid = threadIdx.x;
    const int wave = tid >> 6, lane = tid & 63;
    const int rowbase = blockIdx.x * ROWS;
    const int cl = lane & 15, quad = lane >> 4;

    // --- stage: 8 rows/wave, RAW bf16 cast (no normalization needed for argmax);
    //     row norm computed only for invnorm (update path).
    for (int rr = 0; rr < 8; ++rr) {
        const int rloc = wave * 8 + rr;
        const float* src = emb + (size_t)(rowbase + rloc) * D + lane * 8;
        float4 v0 = *(const float4*)src;
        float4 v1 = *(const float4*)(src + 4);
        float ss = v0.x*v0.x + v0.y*v0.y + v0.z*v0.z + v0.w*v0.w
                 + v1.x*v1.x + v1.y*v1.y + v1.z*v1.z + v1.w*v1.w;
        #pragma unroll
        for (int off = 32; off > 0; off >>= 1) ss += __shfl_xor(ss, off, 64);
        if (lane == 0) invnorm[rowbase + rloc] = 1.0f / fmaxf(sqrtf(ss), 1e-6f);
        ushort8 w;
        w[0] = f2bf(v0.x); w[1] = f2bf(v0.y); w[2] = f2bf(v0.z); w[3] = f2bf(v0.w);
        w[4] = f2bf(v1.x); w[5] = f2bf(v1.y); w[6] = f2bf(v1.z); w[7] = f2bf(v1.w);
        const int slot = lane ^ (rloc & 7);
        *(ushort8*)(&eT[rloc * D + slot * 8]) = w;
    }
    __syncthreads();

    // --- main: wave owns protos [wave*128, +128) in 2 groups of 64
    for (int ng = 0; ng < 2; ++ng) {
        const int colbase = wave * 128 + ng * 64;
        const unsigned short* bg = pbf + (size_t)colbase * 512 + lane * 8;
        f32x4 acc[4][4];
        #pragma unroll
        for (int m = 0; m < 4; ++m)
            #pragma unroll
            for (int n = 0; n < 4; ++n) acc[m][n] = (f32x4){0.f, 0.f, 0.f, 0.f};

        for (int ks = 0; ks < 16; ++ks) {
            bfrag8 a[4], b[4];
            #pragma unroll
            for (int m = 0; m < 4; ++m) {
                const int rloc = m * 16 + cl;
                const int slot = (ks * 4 + quad) ^ (cl & 7);
                a[m] = *(const bfrag8*)(&eT[rloc * D + slot * 8]);
            }
            #pragma unroll
            for (int n = 0; n < 4; ++n)
                b[n] = *(const bfrag8*)(bg + n * 8192 + ks * 512);   // 1KB coalesced
            #pragma unroll
            for (int n = 0; n < 4; ++n)
                #pragma unroll
                for (int m = 0; m < 4; ++m)
                    acc[m][n] = __builtin_amdgcn_mfma_f32_16x16x32_bf16(a[m], b[n], acc[m][n], 0, 0, 0);
        }

        // fold this group (C layout: col=lane&15, row=quad*4+reg) straight to LDS.
        // n ascending -> idx ascending -> strict > keeps first max (jnp.argmax).
        #pragma unroll
        for (int m = 0; m < 4; ++m)
            #pragma unroll
            for (int r = 0; r < 4; ++r) {
                float v = acc[m][0][r];
                int idx = colbase + cl;
                #pragma unroll
                for (int n = 1; n < 4; ++n) {
                    const float c = acc[m][n][r];
                    const int ci = colbase + n * 16 + cl;
                    if (c > v) { v = c; idx = ci; }
                }
                #pragma unroll
                for (int off = 1; off < 16; off <<= 1) {
                    const float ov = __shfl_xor(v, off, 64);
                    const int   oi = __shfl_xor(idx, off, 64);
                    if (ov > v || (ov == v && oi < idx)) { v = ov; idx = oi; }
                }
                if (cl == 0) {
                    swmax[wave * 2 + ng][m * 16 + quad * 4 + r] = v;
                    swidx[wave * 2 + ng][m * 16 + quad * 4 + r] = idx;
                }
            }
    }
    __syncthreads();

    // --- merge 16 slots (slot s covers protos [s*64,(s+1)*64): idx-ascending)
    if (tid < 64) {
        float v = swmax[0][tid]; int idx = swidx[0][tid];
        #pragma unroll
        for (int s = 1; s < 16; ++s) {
            const float ov = swmax[s][tid];
            const int   oi = swidx[s][tid];
            if (ov > v || (ov == v && oi < idx)) { v = ov; idx = oi; }
        }
        assign[rowbase + tid] = idx;
        atomicAdd(&counts[idx], 1);
    }
}

// ---------------- k2: exclusive prefix sum of counts ----------------
__global__ __launch_bounds__(1024) void prefix_kernel(
    const int* __restrict__ counts, int* __restrict__ offsets, int* __restrict__ cursor)
{
    __shared__ int sc[NPROTO];
    const int t = threadIdx.x;
    const int c = counts[t];
    sc[t] = c;
    __syncthreads();
    #pragma unroll
    for (int off = 1; off < NPROTO; off <<= 1) {
        const int v = (t >= off) ? sc[t - off] : 0;
        __syncthreads();
        sc[t] += v;
        __syncthreads();
    }
    const int excl = sc[t] - c;
    offsets[t] = excl;
    cursor[t]  = excl;
}

// ---------------- k3: scatter row indices into per-proto bins ----------------
__global__ __launch_bounds__(256) void scatter_kernel(
    const int* __restrict__ assign, int* __restrict__ cursor, int* __restrict__ bin)
{
    const int i = blockIdx.x * 256 + threadIdx.x;
    const int k = assign[i];
    const int pos = atomicAdd(&cursor[k], 1);
    bin[pos] = i;
}

// ---------------- k4: per-proto gather mean + EMA + normalize ----------------
// 256 threads: parity (t>>7) selects row, (t&127)*4 selects float4 col group.
__global__ __launch_bounds__(256) void update_kernel(
    const float* __restrict__ emb, const float* __restrict__ protos,
    const int* __restrict__ bin, const int* __restrict__ counts,
    const int* __restrict__ offsets, const float* __restrict__ invnorm,
    float* __restrict__ out)
{
    __shared__ float4 part[128];
    __shared__ float red[2];
    const int k = blockIdx.x, t = threadIdx.x;
    const int cnt = counts[k], off = offsets[k];
    const int par = t >> 7, colg = (t & 127) * 4;
    float4 acc = make_float4(0.f, 0.f, 0.f, 0.f);

    int jb = 0;
    for (; jb + 4 <= cnt; jb += 4) {
        const int r0 = bin[off + jb + par];
        const int r1 = bin[off + jb + 2 + par];
        const float s0 = invnorm[r0], s1 = invnorm[r1];
        const float4 v0 = *(const float4*)(emb + (size_t)r0 * D + colg);
        const float4 v1 = *(const float4*)(emb + (size_t)r1 * D + colg);
        acc.x += v0.x * s0; acc.y += v0.y * s0; acc.z += v0.z * s0; acc.w += v0.w * s0;
        acc.x += v1.x * s1; acc.y += v1.y * s1; acc.z += v1.z * s1; acc.w += v1.w * s1;
    }
    if (jb + 2 <= cnt) {
        const int r = bin[off + jb + par];
        const float s = invnorm[r];
        const float4 v = *(const float4*)(emb + (size_t)r * D + colg);
        acc.x += v.x * s; acc.y += v.y * s; acc.z += v.z * s; acc.w += v.w * s;
        jb += 2;
    }
    if (par == 0 && jb < cnt) {
        const int r = bin[off + jb];
        const float s = invnorm[r];
        const float4 v = *(const float4*)(emb + (size_t)r * D + colg);
        acc.x += v.x * s; acc.y += v.y * s; acc.z += v.z * s; acc.w += v.w * s;
    }

    if (par == 1) part[t & 127] = acc;
    __syncthreads();

    float4 u, p4;
    float ss = 0.f;
    if (par == 0) {
        const float4 o = part[t];
        acc.x += o.x; acc.y += o.y; acc.z += o.z; acc.w += o.w;
        const float denom = fmaxf((float)cnt, 1.0f);
        p4 = *(const float4*)(protos + (size_t)k * D + colg);
        u.x = 0.9f * p4.x + 0.1f * acc.x / denom;
        u.y = 0.9f * p4.y + 0.1f * acc.y / denom;
        u.z = 0.9f * p4.z + 0.1f * acc.z / denom;
        u.w = 0.9f * p4.w + 0.1f * acc.w / denom;
        ss = u.x*u.x + u.y*u.y + u.z*u.z + u.w*u.w;
    }
    #pragma unroll
    for (int o2 = 32; o2 > 0; o2 >>= 1) ss += __shfl_xor(ss, o2, 64);
    if ((t & 63) == 0 && par == 0) red[t >> 6] = ss;
    __syncthreads();
    if (par == 0) {
        const float tot = red[0] + red[1];
        const float inv = 1.0f / fmaxf(sqrtf(tot), 1e-6f);
        float4 o;
        o.x = (cnt > 0) ? u.x * inv : p4.x;
        o.y = (cnt > 0) ? u.y * inv : p4.y;
        o.z = (cnt > 0) ? u.z * inv : p4.z;
        o.w = (cnt > 0) ? u.w * inv : p4.w;
        *(float4*)(out + (size_t)k * D + colg) = o;
    }
}

extern "C" void kernel_launch(void* const* d_in, const int* in_sizes, int n_in,
                              void* d_out, int out_size, void* d_ws, size_t ws_size,
                              hipStream_t stream)
{
    const float* emb    = (const float*)d_in[0];
    const float* protos = (const float*)d_in[1];
    float* out = (float*)d_out;
    const int n_emb = in_sizes[0] / D;        // 131072

    char* ws = (char*)d_ws;
    unsigned short* pbf = (unsigned short*)ws;                 // 1 MB packed bf16 protos
    int*   assign  = (int*)  (ws + (1 << 20));                 // 512 KB
    float* invnorm = (float*)(ws + (1 << 20) + (512 << 10));   // 512 KB
    int*   counts  = (int*)  (ws + (2 << 20));                 // 4 KB
    int*   offsets = (int*)  (ws + (2 << 20) + (4 << 10));     // 4 KB
    int*   cursor  = (int*)  (ws + (2 << 20) + (8 << 10));     // 4 KB
    int*   bin     = (int*)  (ws + (2 << 20) + (12 << 10));    // 512 KB

    norm_protos_kernel<<<NPROTO / 4, 256, 0, stream>>>(protos, pbf, counts);
    assign_kernel<<<n_emb / ROWS, 512, 0, stream>>>(emb, pbf, assign, invnorm, counts);
    prefix_kernel<<<1, 1024, 0, stream>>>(counts, offsets, cursor);
    scatter_kernel<<<n_emb / 256, 256, 0, stream>>>(assign, cursor, bin);
    update_kernel<<<NPROTO, 256, 0, stream>>>(emb, protos, bin, counts, offsets, invnorm, out);
}

// Round 4
// 532.649 us; speedup vs baseline: 2.1552x; 2.1552x over previous
//
#include <hip/hip_runtime.h>

// PrototypeBank steady-state update, MI355X/gfx950.  Round 4.
//   emb:    [131072, 512] fp32   protos: [1024, 512] fp32
//   out[k]: count>0 ? normalize(0.9*p + 0.1*mean(norm_emb assigned to k)) : p
//
// Round-4 changes:
//   - assign: 32x32x16 MFMA with PROTOS as A (M dim), EMB as B (N dim).
//     Argmax over protos is now an in-register fold over the C rows (known
//     ascending index order) + one shfl_xor(32) half merge — no persistent
//     cross-tile argmax registers, no big shuffle trees.  ~100 live regs
//     under the 128 cap -> no scratch spills (R2/R3 spilled 0.2-1 GB).
//   - update: segmented.  prefix builds a work-item list of <=256-row
//     segments; psum_kernel atomically accumulates partial sums into a
//     zeroed psum[1024][512]; final_kernel does EMA+normalize.  Removes the
//     serial hot-bin tail (~325 us in R1-R3).

#define D 512
#define NPROTO 1024
#define ROWS 64          // embedding rows per workgroup in k1

typedef __attribute__((ext_vector_type(8)))  unsigned short ushort8;
typedef __attribute__((ext_vector_type(8)))  __bf16 bfrag8;
typedef __attribute__((ext_vector_type(16))) float f32x16;

static __device__ inline unsigned short f2bf(float f) {
    unsigned int u = __float_as_uint(f);
    u = u + 0x7FFFu + ((u >> 16) & 1u);   // round-to-nearest-even
    return (unsigned short)(u >> 16);
}

// ---------------- k0: normalize prototypes -> packed bf16 A-fragments ----------------
// Packed for 32x32x16 A-operand: group g32 = p>>5 (32 protos), k-step ks (16 cols).
// Consumer lane l reads ((g32*32+ks)*64 + l)*8 shorts: lane l -> proto g32*32+(l&31),
// k = ks*16 + (l>>5)*8.  Same k-order convention used for B, so any k permutation
// is consistent across operands.
__global__ __launch_bounds__(256) void norm_protos_kernel(
    const float* __restrict__ protos, unsigned short* __restrict__ pbf,
    int* __restrict__ counts)
{
    const int wave = threadIdx.x >> 6, lane = threadIdx.x & 63;
    const int row = blockIdx.x * 4 + wave;            // grid 256 -> 1024 rows
    const float* src = protos + (size_t)row * D + lane * 8;
    float4 v0 = *(const float4*)src;
    float4 v1 = *(const float4*)(src + 4);
    float ss = v0.x*v0.x + v0.y*v0.y + v0.z*v0.z + v0.w*v0.w
             + v1.x*v1.x + v1.y*v1.y + v1.z*v1.z + v1.w*v1.w;
    #pragma unroll
    for (int off = 32; off > 0; off >>= 1) ss += __shfl_xor(ss, off, 64);
    const float inv = 1.0f / fmaxf(sqrtf(ss), 1e-6f);
    ushort8 w;
    w[0] = f2bf(v0.x*inv); w[1] = f2bf(v0.y*inv); w[2] = f2bf(v0.z*inv); w[3] = f2bf(v0.w*inv);
    w[4] = f2bf(v1.x*inv); w[5] = f2bf(v1.y*inv); w[6] = f2bf(v1.z*inv); w[7] = f2bf(v1.w*inv);
    // lane holds k-chunk c = lane (8 bf16): ks = c>>1, half = c&1
    const size_t dst = (size_t)(row >> 5) * 16384 + (lane >> 1) * 512
                     + (lane & 1) * 256 + (row & 31) * 8;
    *(ushort8*)(pbf + dst) = w;
    if (blockIdx.x == 0) ((int4*)counts)[threadIdx.x] = (int4){0, 0, 0, 0};
}

// ---------------- k1: argmax over 1024 protos (32x32x16 bf16 MFMA) ----------------
// LDS B-tile: 64 emb rows x 512 bf16, 16B-chunk XOR swizzle slot = c ^ (row&7).
// 8 waves; wave = 64 protos x 64 emb cols; 2 ng passes cover 1024 protos.
__global__ __launch_bounds__(512, 4) void assign_kernel(
    const float* __restrict__ emb, const unsigned short* __restrict__ pbf,
    int* __restrict__ assign, float* __restrict__ invnorm, int* __restrict__ counts)
{
    __shared__ __align__(16) unsigned short eT[ROWS * D];   // 64 KB
    __shared__ float swmax[8][64];                           // 2 KB
    __shared__ int   swidx[8][64];                           // 2 KB
    const int tid = threadIdx.x;
    const int wave = tid >> 6, lane = tid & 63;
    const int rowbase = blockIdx.x * ROWS;
    const int c32 = lane & 31, h = lane >> 5;

    // --- stage: 8 rows/wave, RAW bf16 (||e|| doesn't change argmax); invnorm saved.
    for (int rr = 0; rr < 8; ++rr) {
        const int rloc = wave * 8 + rr;
        const float* src = emb + (size_t)(rowbase + rloc) * D + lane * 8;
        float4 v0 = *(const float4*)src;
        float4 v1 = *(const float4*)(src + 4);
        float ss = v0.x*v0.x + v0.y*v0.y + v0.z*v0.z + v0.w*v0.w
                 + v1.x*v1.x + v1.y*v1.y + v1.z*v1.z + v1.w*v1.w;
        #pragma unroll
        for (int off = 32; off > 0; off >>= 1) ss += __shfl_xor(ss, off, 64);
        if (lane == 0) invnorm[rowbase + rloc] = 1.0f / fmaxf(sqrtf(ss), 1e-6f);
        ushort8 w;
        w[0] = f2bf(v0.x); w[1] = f2bf(v0.y); w[2] = f2bf(v0.z); w[3] = f2bf(v0.w);
        w[4] = f2bf(v1.x); w[5] = f2bf(v1.y); w[6] = f2bf(v1.z); w[7] = f2bf(v1.w);
        const int slot = lane ^ (rloc & 7);
        *(ushort8*)(&eT[rloc * D + slot * 8]) = w;
    }
    __syncthreads();

    float rv0 = -3.4e38f, rv1 = -3.4e38f;
    int   ri0 = 0,        ri1 = 0;

    // B LDS addresses: row r0=c32 (nt0), r1=32+c32 (nt1); (r0&7)==(r1&7)==(c32&7)
    const int bbase0 = c32 * D;            // shorts
    const int bbase1 = (32 + c32) * D;
    const int rxor = c32 & 7;

    for (int ng = 0; ng < 2; ++ng) {
        const int pbase = ng * 512 + wave * 64;
        const unsigned short* pa0 = pbf + (size_t)(pbase >> 5) * 16384 + lane * 8;
        const unsigned short* pa1 = pa0 + 16384;

        f32x16 acc00 = (f32x16)(0.f), acc01 = (f32x16)(0.f);
        f32x16 acc10 = (f32x16)(0.f), acc11 = (f32x16)(0.f);

        #pragma unroll 2
        for (int ks = 0; ks < 32; ++ks) {
            const bfrag8 a0 = *(const bfrag8*)(pa0 + ks * 512);
            const bfrag8 a1 = *(const bfrag8*)(pa1 + ks * 512);
            const int slot = ((ks * 2 + h) ^ rxor) * 8;
            const bfrag8 b0 = *(const bfrag8*)(&eT[bbase0 + slot]);
            const bfrag8 b1 = *(const bfrag8*)(&eT[bbase1 + slot]);
            acc00 = __builtin_amdgcn_mfma_f32_32x32x16_bf16(a0, b0, acc00, 0, 0, 0);
            acc01 = __builtin_amdgcn_mfma_f32_32x32x16_bf16(a0, b1, acc01, 0, 0, 0);
            acc10 = __builtin_amdgcn_mfma_f32_32x32x16_bf16(a1, b0, acc10, 0, 0, 0);
            acc11 = __builtin_amdgcn_mfma_f32_32x32x16_bf16(a1, b1, acc11, 0, 0, 0);
        }

        // In-register argmax over protos.  C layout (32x32): col=lane&31,
        // row = (reg&3) + 8*(reg>>2) + 4*(lane>>5).  For fixed lane, iterating
        // reg 0..15 then mt 0..1 gives strictly ascending proto index ->
        // strict > keeps the first max (jnp.argmax semantics).
        float bv0 = -3.4e38f, bv1 = -3.4e38f;
        int   bi0 = 0,        bi1 = 0;
        #pragma unroll
        for (int j = 0; j < 16; ++j) {
            const int row = (j & 3) + 8 * (j >> 2) + 4 * h;
            const float v0 = acc00[j], v1 = acc01[j];
            if (v0 > bv0) { bv0 = v0; bi0 = pbase + row; }
            if (v1 > bv1) { bv1 = v1; bi1 = pbase + row; }
        }
        #pragma unroll
        for (int j = 0; j < 16; ++j) {
            const int row = 32 + (j & 3) + 8 * (j >> 2) + 4 * h;
            const float v0 = acc10[j], v1 = acc11[j];
            if (v0 > bv0) { bv0 = v0; bi0 = pbase + row; }
            if (v1 > bv1) { bv1 = v1; bi1 = pbase + row; }
        }
        // half-merge (other half owns interleaved rows; tie-break on index)
        {
            const float ov = __shfl_xor(bv0, 32, 64);
            const int   oi = __shfl_xor(bi0, 32, 64);
            if (ov > bv0 || (ov == bv0 && oi < bi0)) { bv0 = ov; bi0 = oi; }
        }
        {
            const float ov = __shfl_xor(bv1, 32, 64);
            const int   oi = __shfl_xor(bi1, 32, 64);
            if (ov > bv1 || (ov == bv1 && oi < bi1)) { bv1 = ov; bi1 = oi; }
        }
        // ng ascending: strictly-greater replaces; ties keep older (smaller idx)
        if (bv0 > rv0) { rv0 = bv0; ri0 = bi0; }
        if (bv1 > rv1) { rv1 = bv1; ri1 = bi1; }
    }

    if (h == 0) {
        swmax[wave][c32]      = rv0;  swidx[wave][c32]      = ri0;
        swmax[wave][32 + c32] = rv1;  swidx[wave][32 + c32] = ri1;
    }
    __syncthreads();

    if (tid < 64) {
        float v = swmax[0][tid]; int idx = swidx[0][tid];
        #pragma unroll
        for (int w = 1; w < 8; ++w) {
            const float ov = swmax[w][tid];
            const int   oi = swidx[w][tid];
            if (ov > v || (ov == v && oi < idx)) { v = ov; idx = oi; }
        }
        assign[rowbase + tid] = idx;
        atomicAdd(&counts[idx], 1);
    }
}

// ---------------- k2: prefix sum + segment work-item list ----------------
__global__ __launch_bounds__(1024) void prefix_kernel(
    const int* __restrict__ counts, int* __restrict__ offsets,
    int* __restrict__ cursor, int* __restrict__ items, int* __restrict__ nitems)
{
    __shared__ int sc[NPROTO];
    const int t = threadIdx.x;
    const int c = counts[t];
    sc[t] = c;
    __syncthreads();
    #pragma unroll
    for (int off = 1; off < NPROTO; off <<= 1) {
        const int v = (t >= off) ? sc[t - off] : 0;
        __syncthreads();
        sc[t] += v;
        __syncthreads();
    }
    const int excl = sc[t] - c;
    offsets[t] = excl;
    cursor[t]  = excl;

    // second scan: segments of <=256 rows
    const int nseg = (c + 255) >> 8;
    __syncthreads();
    sc[t] = nseg;
    __syncthreads();
    #pragma unroll
    for (int off = 1; off < NPROTO; off <<= 1) {
        const int v = (t >= off) ? sc[t - off] : 0;
        __syncthreads();
        sc[t] += v;
        __syncthreads();
    }
    const int segexcl = sc[t] - nseg;
    for (int s = 0; s < nseg; ++s) items[segexcl + s] = (t << 12) | s;
    if (t == NPROTO - 1) *nitems = sc[NPROTO - 1];
}

// ---------------- k3: scatter row indices into per-proto bins ----------------
__global__ __launch_bounds__(256) void scatter_kernel(
    const int* __restrict__ assign, int* __restrict__ cursor, int* __restrict__ bin)
{
    const int i = blockIdx.x * 256 + threadIdx.x;
    const int k = assign[i];
    const int pos = atomicAdd(&cursor[k], 1);
    bin[pos] = i;
}

// ---------------- k4A: per-segment partial sums -> psum (atomic fp32) ----------------
__global__ __launch_bounds__(256) void psum_kernel(
    const float* __restrict__ emb, const int* __restrict__ bin,
    const int* __restrict__ counts, const int* __restrict__ offsets,
    const float* __restrict__ invnorm, const int* __restrict__ items,
    const int* __restrict__ nitems, float* __restrict__ psum)
{
    if ((int)blockIdx.x >= *nitems) return;
    __shared__ float4 part[128];
    const int item = items[blockIdx.x];
    const int k = item >> 12, seg = item & 4095;
    const int off = offsets[k], cnt = counts[k];
    const int s0 = seg * 256;
    const int s1 = min(s0 + 256, cnt);
    const int t = threadIdx.x;
    const int par = t >> 7, colg = (t & 127) * 4;
    float4 acc = make_float4(0.f, 0.f, 0.f, 0.f);

    int jb = s0;
    for (; jb + 4 <= s1; jb += 4) {
        const int r0 = bin[off + jb + par];
        const int r1 = bin[off + jb + 2 + par];
        const float sc0 = invnorm[r0], sc1 = invnorm[r1];
        const float4 v0 = *(const float4*)(emb + (size_t)r0 * D + colg);
        const float4 v1 = *(const float4*)(emb + (size_t)r1 * D + colg);
        acc.x += v0.x * sc0; acc.y += v0.y * sc0; acc.z += v0.z * sc0; acc.w += v0.w * sc0;
        acc.x += v1.x * sc1; acc.y += v1.y * sc1; acc.z += v1.z * sc1; acc.w += v1.w * sc1;
    }
    if (jb + 2 <= s1) {
        const int r = bin[off + jb + par];
        const float sc = invnorm[r];
        const float4 v = *(const float4*)(emb + (size_t)r * D + colg);
        acc.x += v.x * sc; acc.y += v.y * sc; acc.z += v.z * sc; acc.w += v.w * sc;
        jb += 2;
    }
    if (par == 0 && jb < s1) {
        const int r = bin[off + jb];
        const float sc = invnorm[r];
        const float4 v = *(const float4*)(emb + (size_t)r * D + colg);
        acc.x += v.x * sc; acc.y += v.y * sc; acc.z += v.z * sc; acc.w += v.w * sc;
    }

    if (par == 1) part[t & 127] = acc;
    __syncthreads();
    if (par == 0) {
        const float4 o = part[t];
        float* dst = psum + (size_t)k * D + colg;
        atomicAdd(dst + 0, acc.x + o.x);
        atomicAdd(dst + 1, acc.y + o.y);
        atomicAdd(dst + 2, acc.z + o.z);
        atomicAdd(dst + 3, acc.w + o.w);
    }
}

// ---------------- k4B: EMA + normalize ----------------
__global__ __launch_bounds__(128) void final_kernel(
    const float* __restrict__ protos, const float* __restrict__ psum,
    const int* __restrict__ counts, float* __restrict__ out)
{
    __shared__ float red[2];
    const int k = blockIdx.x, t = threadIdx.x;
    const int colg = t * 4;
    const int cnt = counts[k];
    const float denom = fmaxf((float)cnt, 1.0f);
    const float4 s  = *(const float4*)(psum + (size_t)k * D + colg);
    const float4 p4 = *(const float4*)(protos + (size_t)k * D + colg);
    float4 u;
    u.x = 0.9f * p4.x + 0.1f * s.x / denom;
    u.y = 0.9f * p4.y + 0.1f * s.y / denom;
    u.z = 0.9f * p4.z + 0.1f * s.z / denom;
    u.w = 0.9f * p4.w + 0.1f * s.w / denom;
    float ss = u.x*u.x + u.y*u.y + u.z*u.z + u.w*u.w;
    #pragma unroll
    for (int off = 32; off > 0; off >>= 1) ss += __shfl_xor(ss, off, 64);
    if ((t & 63) == 0) red[t >> 6] = ss;
    __syncthreads();
    const float tot = red[0] + red[1];
    const float inv = 1.0f / fmaxf(sqrtf(tot), 1e-6f);
    float4 o;
    o.x = (cnt > 0) ? u.x * inv : p4.x;
    o.y = (cnt > 0) ? u.y * inv : p4.y;
    o.z = (cnt > 0) ? u.z * inv : p4.z;
    o.w = (cnt > 0) ? u.w * inv : p4.w;
    *(float4*)(out + (size_t)k * D + colg) = o;
}

extern "C" void kernel_launch(void* const* d_in, const int* in_sizes, int n_in,
                              void* d_out, int out_size, void* d_ws, size_t ws_size,
                              hipStream_t stream)
{
    const float* emb    = (const float*)d_in[0];
    const float* protos = (const float*)d_in[1];
    float* out = (float*)d_out;
    const int n_emb = in_sizes[0] / D;        // 131072

    char* ws = (char*)d_ws;
    unsigned short* pbf = (unsigned short*)ws;                 // 1 MB packed bf16 protos
    int*   assign  = (int*)  (ws + (1 << 20));                 // 512 KB
    float* invnorm = (float*)(ws + (1 << 20) + (512 << 10));   // 512 KB
    int*   counts  = (int*)  (ws + (2 << 20));                 // 4 KB
    int*   offsets = (int*)  (ws + (2 << 20) + (4 << 10));     // 4 KB
    int*   cursor  = (int*)  (ws + (2 << 20) + (8 << 10));     // 4 KB
    int*   nitems  = (int*)  (ws + (2 << 20) + (12 << 10));    // 4 KB
    int*   items   = (int*)  (ws + (2 << 20) + (16 << 10));    // 8 KB (<=1536)
    int*   bin     = (int*)  (ws + (2 << 20) + (24 << 10));    // 512 KB
    float* psum    = (float*)(ws + (2 << 20) + (24 << 10) + (512 << 10)); // 2 MB

    hipMemsetAsync(psum, 0, NPROTO * D * sizeof(float), stream);
    norm_protos_kernel<<<NPROTO / 4, 256, 0, stream>>>(protos, pbf, counts);
    assign_kernel<<<n_emb / ROWS, 512, 0, stream>>>(emb, pbf, assign, invnorm, counts);
    prefix_kernel<<<1, 1024, 0, stream>>>(counts, offsets, cursor, items, nitems);
    scatter_kernel<<<n_emb / 256, 256, 0, stream>>>(assign, cursor, bin);
    psum_kernel<<<1536, 256, 0, stream>>>(emb, bin, counts, offsets, invnorm,
                                          items, nitems, psum);
    final_kernel<<<NPROTO, 128, 0, stream>>>(protos, psum, counts, out);
}